// Round 8
// baseline (5585.629 us; speedup 1.0000x reference)
//
#include <hip/hip_runtime.h>
#include <cstdint>
#include <cstddef>

typedef __attribute__((ext_vector_type(4)))  int   i32x4;
typedef __attribute__((ext_vector_type(16))) int   i32x16;
typedef __attribute__((ext_vector_type(4)))  float f32x4;

// Problem dims (fixed by setup_inputs: B=8, S=2048, K=4096, O=4096)
#define M_DIM 16384
#define N_DIM 4096
#define K_DIM 4096
#define NT    (K_DIM / 128)   // 32 K-tiles of 128 int8 (= 4 MFMA K=32 slices)

// Compiler-fenced barrier / waits (full compiler memory fence at rendezvous).
#define BARRIER() asm volatile("s_barrier" ::: "memory")

// ---------------------------------------------------------------------------
// quantize x (per-tensor): xq = clip(rint(x/s)+zp, -128,127) - zp
// ---------------------------------------------------------------------------
__global__ __launch_bounds__(256) void quant_x_kernel(
    const float* __restrict__ x,
    const float* __restrict__ act_scale,
    const int*   __restrict__ act_zp,
    signed char* __restrict__ xq)
{
    int idx = blockIdx.x * 256 + threadIdx.x;      // one thread per 16 elems
    float s   = act_scale[0];
    float zpf = (float)act_zp[0];
    const f32x4* xp = (const f32x4*)(x + (size_t)idx * 16);
    union { signed char c[16]; i32x4 v; } u;
#pragma unroll
    for (int j = 0; j < 4; ++j) {
        f32x4 v = xp[j];
#pragma unroll
        for (int e = 0; e < 4; ++e) {
            float q = rintf(v[e] / s) + zpf;          // round-half-even like np.round
            q = fminf(fmaxf(q, -128.f), 127.f);
            u.c[j * 4 + e] = (signed char)(int)(q - zpf);
        }
    }
    *(i32x4*)(xq + (size_t)idx * 16) = u.v;
}

// ---------------------------------------------------------------------------
// quantize weight (per-output-row scale/zp). K_DIM=4096 -> 256 threads/row.
// ---------------------------------------------------------------------------
__global__ __launch_bounds__(256) void quant_w_kernel(
    const float* __restrict__ w,
    const float* __restrict__ wscale,
    const int*   __restrict__ wzp,
    signed char* __restrict__ wq)
{
    int idx = blockIdx.x * 256 + threadIdx.x;
    int row = idx >> 8;                             // 4096/16 = 256 chunks per row
    float s   = wscale[row];
    float zpf = (float)wzp[row];
    const f32x4* wp = (const f32x4*)(w + (size_t)idx * 16);
    union { signed char c[16]; i32x4 v; } u;
#pragma unroll
    for (int j = 0; j < 4; ++j) {
        f32x4 v = wp[j];
#pragma unroll
        for (int e = 0; e < 4; ++e) {
            float q = rintf(v[e] / s) + zpf;
            q = fminf(fmaxf(q, -128.f), 127.f);
            u.c[j * 4 + e] = (signed char)(int)(q - zpf);
        }
    }
    *(i32x4*)(wq + (size_t)idx * 16) = u.v;
}

// ---------------------------------------------------------------------------
// int8 GEMM 256x256 with mfma_i32_32x32x32_i8, K-SLICED SINGLE-BUFFER LDS.
//
// LDS 64 KiB (-> 2 blocks/CU, 4 waves/SIMD: the other block's waves run
// during this block's barrier/vmcnt drains -- the structural fix for the
// 1-block phase-locked convoys at 128 KiB):
//   A slice s (s=0..3): [s*8192, s*8192+8192)  = 256 rows x 32 B (K-slice)
//   B slice s:          [32768 + s*8192, ...)
// One global_load_lds call stages one whole slice (512 thr x 16 B = 8 KiB).
//
// Pipeline (phase s of tile t, phi = 4t+s): stage slice s of t+1 (overwrites
// region whose readers drained at end of phase s-1); read slice s+1 frags
// (tile t for s<3, tile t+1 for s==3 -- region already holds t+1's data,
// staged at phi-3); MFMA slice s (frags read last phase); per-phase-end:
// lgkmcnt(0) [drain own reads], vmcnt(4) [retire stage phi-2 -> read at
// phi+1 safe], barrier. Tail t=NT-1: vmcnt(2)@s0, vmcnt(0)@s1.
// Frag reg sets ping-pong by phase parity (static names, rule #20).
//
// Swizzle (32B-row slices): LDS addr(row,g) = row*32 + (g ^ row[2])*16,
// g = k-16B-half = lane>>5 on read. 8 consecutive lanes (rows) hit all 8
// 16B slots -> conflict-free (same class as verified round-3 XOR).
// Stage inverse: thread tid writes LDS tid*16 from global row=tid>>1,
// g=(tid&1)^((tid>>3)&1).
//
// mfma_i32_32x32x32_i8: A/B 4 regs (16B: row=lane&31, k-16B-half=lane>>5);
// C/D 16 regs: col=lane&31, row=(reg&3)+8*(reg>>2)+4*(lane>>5) (guide-
// verified, dtype-independent). Per wave: 4 mf x 2 nf frags = 128x64 out.
// ---------------------------------------------------------------------------
__global__ __launch_bounds__(512, 4) void gemm_i8_256(
    const signed char* __restrict__ Aq,
    const signed char* __restrict__ Bq,
    const float* __restrict__ bias,
    const float* __restrict__ act_scale,
    const float* __restrict__ wscale,
    float* __restrict__ out)
{
    __shared__ signed char lds[65536];   // 64 KiB -> 2 blocks/CU

    const int nbn = N_DIM / 256;                 // 16
    const int nwg = (M_DIM / 256) * nbn;         // 1024, %8==0
    int bid = blockIdx.x;
    int wg  = (bid & 7) * (nwg >> 3) + (bid >> 3);   // T1 XCD swizzle, bijective
    int bm  = wg / nbn;
    int bn  = wg % nbn;

    int tid  = threadIdx.x;
    int wave = tid >> 6;
    int lane = tid & 63;
    int wm_i = wave >> 2;      // 0..1  (128-row half)
    int wn_i = wave & 3;       // 0..3  (64-col quarter)

    const signed char* Ag = Aq + (size_t)bm * 256 * K_DIM;
    const signed char* Bg = Bq + (size_t)bn * 256 * K_DIM;

    // ---- staging source (per-thread): row = tid>>1, g = (tid&1)^((tid>>3)&1)
    size_t soff = (size_t)(tid >> 1) * K_DIM + (((tid & 1) ^ ((tid >> 3) & 1)) * 16);

    // ---- reader fragment bases (swizzle folded; per-lane constants) --------
    int xbit  = (((lane >> 5) ^ ((lane >> 2) & 1)) << 4);
    int abase = wm_i * 4096 + (lane & 31) * 32 + xbit;            // + mf*1024
    int bbase = 32768 + wn_i * 2048 + (lane & 31) * 32 + xbit;    // + nf*1024

    // stage slice s of K-tile `tile` (A and B; 2 VMEM insts per call)
#define STAGE_AB(tile, s) do {                                                       \
    __builtin_amdgcn_global_load_lds(                                                \
        (const __attribute__((address_space(1))) void*)                              \
            (Ag + (size_t)(tile) * 128 + (s) * 32 + soff),                           \
        (__attribute__((address_space(3))) void*)(lds + (s) * 8192 + wave * 1024),   \
        16, 0, 0);                                                                   \
    __builtin_amdgcn_global_load_lds(                                                \
        (const __attribute__((address_space(1))) void*)                              \
            (Bg + (size_t)(tile) * 128 + (s) * 32 + soff),                           \
        (__attribute__((address_space(3))) void*)(lds + 32768 + (s) * 8192           \
                                                  + wave * 1024),                    \
        16, 0, 0);                                                                   \
} while (0)

#define READ_SET(AF, BF, s) do {                                                     \
    _Pragma("unroll")                                                                \
    for (int mf = 0; mf < 4; ++mf)                                                   \
        AF[mf] = *(const i32x4*)(lds + (s) * 8192 + abase + mf * 1024);              \
    _Pragma("unroll")                                                                \
    for (int nf = 0; nf < 2; ++nf)                                                   \
        BF[nf] = *(const i32x4*)(lds + (s) * 8192 + bbase + nf * 1024);              \
} while (0)

#define MFMA_SET(AF, BF) do {                                                        \
    _Pragma("unroll")                                                                \
    for (int mf = 0; mf < 4; ++mf)                                                   \
        _Pragma("unroll")                                                            \
        for (int nf = 0; nf < 2; ++nf)                                               \
            acc[mf][nf] = __builtin_amdgcn_mfma_i32_32x32x32_i8(                     \
                AF[mf], BF[nf], acc[mf][nf], 0, 0, 0);                               \
} while (0)

    i32x16 acc[4][2] = {};
    i32x4 aE[4], bE[2], aO[4], bO[2];   // ping-pong frag sets (phase parity)

    // ---- prologue: stage all 4 slices of tile 0, drain, read slice 0 -------
    STAGE_AB(0, 0); STAGE_AB(0, 1); STAGE_AB(0, 2); STAGE_AB(0, 3);
    asm volatile("s_waitcnt vmcnt(0)" ::: "memory");
    BARRIER();
    READ_SET(aE, bE, 0);                 // set E consumed at phase 0
    asm volatile("s_waitcnt lgkmcnt(0)" ::: "memory");
    BARRIER();

    // phase s: CUR = (s&1 ? O : E), NXT = other. Reads slice (s+1)&3.
#define PHASE(t, s, CA, CB, NA, NB) do {                                             \
    if ((t) + 1 < NT) {                                                              \
        STAGE_AB((t) + 1, (s));                                                      \
        if ((s) == 3) READ_SET(NA, NB, 0);         /* slice0 = tile t+1 data */      \
    }                                                                                \
    if ((s) < 3) READ_SET(NA, NB, (s) + 1);        /* tile t data */                 \
    __builtin_amdgcn_s_setprio(1);                                                   \
    MFMA_SET(CA, CB);                                                                \
    __builtin_amdgcn_s_setprio(0);                                                   \
    asm volatile("s_waitcnt lgkmcnt(0)" ::: "memory");                               \
    if ((t) < NT - 1) {                                                              \
        asm volatile("s_waitcnt vmcnt(4)" ::: "memory");                             \
    } else if ((s) == 0) {                                                           \
        asm volatile("s_waitcnt vmcnt(2)" ::: "memory");                             \
    } else if ((s) == 1) {                                                           \
        asm volatile("s_waitcnt vmcnt(0)" ::: "memory");                             \
    }                                                                                \
    BARRIER();                                                                       \
} while (0)

    for (int t = 0; t < NT; ++t) {
        PHASE(t, 0, aE, bE, aO, bO);
        PHASE(t, 1, aO, bO, aE, bE);
        PHASE(t, 2, aE, bE, aO, bO);
        PHASE(t, 3, aO, bO, aE, bE);
    }
#undef PHASE
#undef MFMA_SET
#undef READ_SET
#undef STAGE_AB

    // ---- epilogue: out = acc * (sa * sw[o]) + bias[o] ----------------------
    float sa = act_scale[0];
#pragma unroll
    for (int nf = 0; nf < 2; ++nf) {
        int o = bn * 256 + wn_i * 64 + nf * 32 + (lane & 31);
        float sw = sa * wscale[o];
        float bv = bias[o];
#pragma unroll
        for (int mf = 0; mf < 4; ++mf) {
            int rowb = bm * 256 + wm_i * 128 + mf * 32 + 4 * (lane >> 5);
#pragma unroll
            for (int r = 0; r < 16; ++r) {
                int grow = rowb + (r & 3) + 8 * (r >> 2);
                out[(size_t)grow * N_DIM + o] = (float)acc[mf][nf][r] * sw + bv;
            }
        }
    }
}

// ---------------------------------------------------------------------------
// insurance fallback if ws_size < 80MB (should never trigger)
// ---------------------------------------------------------------------------
__global__ void fallback_kernel(
    const float* __restrict__ x, const float* __restrict__ w,
    const float* __restrict__ bias,
    const float* __restrict__ act_scale, const float* __restrict__ wscale,
    const int* __restrict__ act_zp, const int* __restrict__ wzp,
    float* __restrict__ out)
{
    size_t idx = (size_t)blockIdx.x * blockDim.x + threadIdx.x;
    if (idx >= (size_t)M_DIM * N_DIM) return;
    int m = (int)(idx >> 12);
    int o = (int)(idx & 4095);
    float sx = act_scale[0], zx = (float)act_zp[0];
    float sw = wscale[o],    zw = (float)wzp[o];
    float acc = 0.f;
    for (int k = 0; k < K_DIM; ++k) {
        float qx = fminf(fmaxf(rintf(x[(size_t)m * K_DIM + k] / sx) + zx, -128.f), 127.f) - zx;
        float qw = fminf(fmaxf(rintf(w[(size_t)o * K_DIM + k] / sw) + zw, -128.f), 127.f) - zw;
        acc += (qx * sx) * (qw * sw);
    }
    out[idx] = acc + bias[o];
}

// ---------------------------------------------------------------------------
extern "C" void kernel_launch(void* const* d_in, const int* in_sizes, int n_in,
                              void* d_out, int out_size, void* d_ws, size_t ws_size,
                              hipStream_t stream)
{
    const float* x    = (const float*)d_in[0];
    const float* w    = (const float*)d_in[1];
    const float* bias = (const float*)d_in[2];
    const float* asc  = (const float*)d_in[3];
    const float* wsc  = (const float*)d_in[4];
    const int*   azp  = (const int*)d_in[5];
    const int*   wzp  = (const int*)d_in[6];
    float* out = (float*)d_out;

    size_t xq_bytes = (size_t)M_DIM * K_DIM;   // 64 MiB
    size_t wq_bytes = (size_t)N_DIM * K_DIM;   // 16 MiB

    if (ws_size < xq_bytes + wq_bytes) {
        int total = M_DIM * N_DIM;
        fallback_kernel<<<(total + 255) / 256, 256, 0, stream>>>(
            x, w, bias, asc, wsc, azp, wzp, out);
        return;
    }

    signed char* xq = (signed char*)d_ws;
    signed char* wq = (signed char*)d_ws + xq_bytes;

    quant_x_kernel<<<(M_DIM * (K_DIM / 16)) / 256, 256, 0, stream>>>(x, asc, azp, xq);
    quant_w_kernel<<<(N_DIM * (K_DIM / 16)) / 256, 256, 0, stream>>>(w, wsc, wzp, wq);
    gemm_i8_256<<<(M_DIM / 256) * (N_DIM / 256), 512, 0, stream>>>(
        xq, wq, bias, asc, wsc, out);
}

// Round 9
// 448.959 us; speedup vs baseline: 12.4413x; 12.4413x over previous
//
#include <hip/hip_runtime.h>
#include <cstdint>
#include <cstddef>

typedef __attribute__((ext_vector_type(4)))  int   i32x4;
typedef __attribute__((ext_vector_type(16))) int   i32x16;
typedef __attribute__((ext_vector_type(4)))  float f32x4;

// Problem dims (fixed by setup_inputs: B=8, S=2048, K=4096, O=4096)
#define M_DIM 16384
#define N_DIM 4096
#define K_DIM 4096
#define NT    (K_DIM / 128)   // 32 K-tiles of 128 int8 (= 4 MFMA K=32 slices)

// Compiler-fenced barrier / waits (full compiler memory fence at rendezvous).
#define BARRIER() asm volatile("s_barrier" ::: "memory")

// ---------------------------------------------------------------------------
// quantize x (per-tensor): xq = clip(rint(x/s)+zp, -128,127) - zp
// ---------------------------------------------------------------------------
__global__ __launch_bounds__(256) void quant_x_kernel(
    const float* __restrict__ x,
    const float* __restrict__ act_scale,
    const int*   __restrict__ act_zp,
    signed char* __restrict__ xq)
{
    int idx = blockIdx.x * 256 + threadIdx.x;      // one thread per 16 elems
    float s   = act_scale[0];
    float zpf = (float)act_zp[0];
    const f32x4* xp = (const f32x4*)(x + (size_t)idx * 16);
    union { signed char c[16]; i32x4 v; } u;
#pragma unroll
    for (int j = 0; j < 4; ++j) {
        f32x4 v = xp[j];
#pragma unroll
        for (int e = 0; e < 4; ++e) {
            float q = rintf(v[e] / s) + zpf;          // round-half-even like np.round
            q = fminf(fmaxf(q, -128.f), 127.f);
            u.c[j * 4 + e] = (signed char)(int)(q - zpf);
        }
    }
    *(i32x4*)(xq + (size_t)idx * 16) = u.v;
}

// ---------------------------------------------------------------------------
// quantize weight (per-output-row scale/zp). K_DIM=4096 -> 256 threads/row.
// ---------------------------------------------------------------------------
__global__ __launch_bounds__(256) void quant_w_kernel(
    const float* __restrict__ w,
    const float* __restrict__ wscale,
    const int*   __restrict__ wzp,
    signed char* __restrict__ wq)
{
    int idx = blockIdx.x * 256 + threadIdx.x;
    int row = idx >> 8;                             // 4096/16 = 256 chunks per row
    float s   = wscale[row];
    float zpf = (float)wzp[row];
    const f32x4* wp = (const f32x4*)(w + (size_t)idx * 16);
    union { signed char c[16]; i32x4 v; } u;
#pragma unroll
    for (int j = 0; j < 4; ++j) {
        f32x4 v = wp[j];
#pragma unroll
        for (int e = 0; e < 4; ++e) {
            float q = rintf(v[e] / s) + zpf;
            q = fminf(fmaxf(q, -128.f), 127.f);
            u.c[j * 4 + e] = (signed char)(int)(q - zpf);
        }
    }
    *(i32x4*)(wq + (size_t)idx * 16) = u.v;
}

// ---------------------------------------------------------------------------
// int8 GEMM 256x256 with mfma_i32_32x32x32_i8, K-SLICED SINGLE-BUFFER LDS.
// Structure identical to round 8 (hardware-verified correct, absmax 1.0);
// the ONLY change is __launch_bounds__(512, 2):
//   ROUND-8 BUG: (512,4) capped the allocator at 128 regs/wave (per-SIMD
//   pool = 512/wave-slot, m69); the 128-AGPR accumulator spilled to scratch
//   (17.7 GB writes, MfmaUtil 2%). (512,2) restores the 256-reg budget
//   (acc 128 AGPR + 48 VGPR frags + addressing ~= 200). 2 blocks/CU is
//   unreachable at this acc size -- the reg pool, not LDS, binds occupancy.
//
// LDS 64 KiB, slices: A s: [s*8192, +8192) = 256 rows x 32 B; B s: 32768+...
// One STAGE_AB call = 2 global_load_lds (A slice + B slice, 8 KiB each).
//
// Pipeline (phase s of tile t, phi=4t+s): STAGE slice s of t+1 (its region's
// readers drained at end of phase s-1); read slice s+1 frags (tile t for
// s<3; s==3 reads slice 0 = tile t+1, staged at phi-3, retired by the
// vmcnt(4) at end of phi-1); MFMA slice s (frags read last phase);
// phase end: lgkmcnt(0) [own reads done -> WAR safe], vmcnt(4) [stage phi-2
// retired], barrier. Tail t=NT-1: vmcnt(2)@s0, vmcnt(0)@s1.
// Frag reg sets ping-pong by phase parity (static names, rule #20).
//
// Swizzle: LDS addr(row) = slice + row*32 + ((g ^ row[2])<<4), g=lane>>5.
// Rows 0-7 -> bank groups {0,8,16,24,4,12,20,28}, each b128 = 4 consecutive
// banks -> all 32 banks exactly once per 8 lanes. Stage inverse: thread tid
// writes LDS tid*16 from global row=tid>>1, g=(tid&1)^((tid>>3)&1).
//
// mfma_i32_32x32x32_i8 (verified on HW, round 8): A/B 4 regs, row=lane&31,
// k-16B-half=lane>>5; C/D 16 regs: col=lane&31, row=(reg&3)+8*(reg>>2)
// +4*(lane>>5). Per wave: 4 mf x 2 nf = 128x64 out.
// ---------------------------------------------------------------------------
__global__ __launch_bounds__(512, 2) void gemm_i8_256(
    const signed char* __restrict__ Aq,
    const signed char* __restrict__ Bq,
    const float* __restrict__ bias,
    const float* __restrict__ act_scale,
    const float* __restrict__ wscale,
    float* __restrict__ out)
{
    __shared__ signed char lds[65536];   // 64 KiB

    const int nbn = N_DIM / 256;                 // 16
    const int nwg = (M_DIM / 256) * nbn;         // 1024, %8==0
    int bid = blockIdx.x;
    int wg  = (bid & 7) * (nwg >> 3) + (bid >> 3);   // T1 XCD swizzle, bijective
    int bm  = wg / nbn;
    int bn  = wg % nbn;

    int tid  = threadIdx.x;
    int wave = tid >> 6;
    int lane = tid & 63;
    int wm_i = wave >> 2;      // 0..1  (128-row half)
    int wn_i = wave & 3;       // 0..3  (64-col quarter)

    const signed char* Ag = Aq + (size_t)bm * 256 * K_DIM;
    const signed char* Bg = Bq + (size_t)bn * 256 * K_DIM;

    // ---- staging source (per-thread): row = tid>>1, g = (tid&1)^((tid>>3)&1)
    size_t soff = (size_t)(tid >> 1) * K_DIM + (((tid & 1) ^ ((tid >> 3) & 1)) * 16);

    // ---- reader fragment bases (swizzle folded; per-lane constants) --------
    int xbit  = (((lane >> 5) ^ ((lane >> 2) & 1)) << 4);
    int abase = wm_i * 4096 + (lane & 31) * 32 + xbit;            // + mf*1024
    int bbase = 32768 + wn_i * 2048 + (lane & 31) * 32 + xbit;    // + nf*1024

    // stage slice s of K-tile `tile` (A and B; 2 VMEM insts per call)
#define STAGE_AB(tile, s) do {                                                       \
    __builtin_amdgcn_global_load_lds(                                                \
        (const __attribute__((address_space(1))) void*)                              \
            (Ag + (size_t)(tile) * 128 + (s) * 32 + soff),                           \
        (__attribute__((address_space(3))) void*)(lds + (s) * 8192 + wave * 1024),   \
        16, 0, 0);                                                                   \
    __builtin_amdgcn_global_load_lds(                                                \
        (const __attribute__((address_space(1))) void*)                              \
            (Bg + (size_t)(tile) * 128 + (s) * 32 + soff),                           \
        (__attribute__((address_space(3))) void*)(lds + 32768 + (s) * 8192           \
                                                  + wave * 1024),                    \
        16, 0, 0);                                                                   \
} while (0)

#define READ_SET(AF, BF, s) do {                                                     \
    _Pragma("unroll")                                                                \
    for (int mf = 0; mf < 4; ++mf)                                                   \
        AF[mf] = *(const i32x4*)(lds + (s) * 8192 + abase + mf * 1024);              \
    _Pragma("unroll")                                                                \
    for (int nf = 0; nf < 2; ++nf)                                                   \
        BF[nf] = *(const i32x4*)(lds + (s) * 8192 + bbase + nf * 1024);              \
} while (0)

#define MFMA_SET(AF, BF) do {                                                        \
    _Pragma("unroll")                                                                \
    for (int mf = 0; mf < 4; ++mf)                                                   \
        _Pragma("unroll")                                                            \
        for (int nf = 0; nf < 2; ++nf)                                               \
            acc[mf][nf] = __builtin_amdgcn_mfma_i32_32x32x32_i8(                     \
                AF[mf], BF[nf], acc[mf][nf], 0, 0, 0);                               \
} while (0)

    i32x16 acc[4][2] = {};
    i32x4 aE[4], bE[2], aO[4], bO[2];   // ping-pong frag sets (phase parity)

    // ---- prologue: stage all 4 slices of tile 0, drain, read slice 0 -------
    STAGE_AB(0, 0); STAGE_AB(0, 1); STAGE_AB(0, 2); STAGE_AB(0, 3);
    asm volatile("s_waitcnt vmcnt(0)" ::: "memory");
    BARRIER();
    READ_SET(aE, bE, 0);                 // set E consumed at phase 0
    asm volatile("s_waitcnt lgkmcnt(0)" ::: "memory");
    BARRIER();

    // phase s: CUR = (s&1 ? O : E), NXT = other. Reads slice (s+1)&3.
#define PHASE(t, s, CA, CB, NA, NB) do {                                             \
    if ((t) + 1 < NT) {                                                              \
        STAGE_AB((t) + 1, (s));                                                      \
        if ((s) == 3) READ_SET(NA, NB, 0);         /* slice0 = tile t+1 data */      \
    }                                                                                \
    if ((s) < 3) READ_SET(NA, NB, (s) + 1);        /* tile t data */                 \
    __builtin_amdgcn_s_setprio(1);                                                   \
    MFMA_SET(CA, CB);                                                                \
    __builtin_amdgcn_s_setprio(0);                                                   \
    asm volatile("s_waitcnt lgkmcnt(0)" ::: "memory");                               \
    if ((t) < NT - 1) {                                                              \
        asm volatile("s_waitcnt vmcnt(4)" ::: "memory");                             \
    } else if ((s) == 0) {                                                           \
        asm volatile("s_waitcnt vmcnt(2)" ::: "memory");                             \
    } else if ((s) == 1) {                                                           \
        asm volatile("s_waitcnt vmcnt(0)" ::: "memory");                             \
    }                                                                                \
    BARRIER();                                                                       \
} while (0)

    for (int t = 0; t < NT; ++t) {
        PHASE(t, 0, aE, bE, aO, bO);
        PHASE(t, 1, aO, bO, aE, bE);
        PHASE(t, 2, aE, bE, aO, bO);
        PHASE(t, 3, aO, bO, aE, bE);
    }
#undef PHASE
#undef MFMA_SET
#undef READ_SET
#undef STAGE_AB

    // ---- epilogue: out = acc * (sa * sw[o]) + bias[o] ----------------------
    float sa = act_scale[0];
#pragma unroll
    for (int nf = 0; nf < 2; ++nf) {
        int o = bn * 256 + wn_i * 64 + nf * 32 + (lane & 31);
        float sw = sa * wscale[o];
        float bv = bias[o];
#pragma unroll
        for (int mf = 0; mf < 4; ++mf) {
            int rowb = bm * 256 + wm_i * 128 + mf * 32 + 4 * (lane >> 5);
#pragma unroll
            for (int r = 0; r < 16; ++r) {
                int grow = rowb + (r & 3) + 8 * (r >> 2);
                out[(size_t)grow * N_DIM + o] = (float)acc[mf][nf][r] * sw + bv;
            }
        }
    }
}

// ---------------------------------------------------------------------------
// insurance fallback if ws_size < 80MB (should never trigger)
// ---------------------------------------------------------------------------
__global__ void fallback_kernel(
    const float* __restrict__ x, const float* __restrict__ w,
    const float* __restrict__ bias,
    const float* __restrict__ act_scale, const float* __restrict__ wscale,
    const int* __restrict__ act_zp, const int* __restrict__ wzp,
    float* __restrict__ out)
{
    size_t idx = (size_t)blockIdx.x * blockDim.x + threadIdx.x;
    if (idx >= (size_t)M_DIM * N_DIM) return;
    int m = (int)(idx >> 12);
    int o = (int)(idx & 4095);
    float sx = act_scale[0], zx = (float)act_zp[0];
    float sw = wscale[o],    zw = (float)wzp[o];
    float acc = 0.f;
    for (int k = 0; k < K_DIM; ++k) {
        float qx = fminf(fmaxf(rintf(x[(size_t)m * K_DIM + k] / sx) + zx, -128.f), 127.f) - zx;
        float qw = fminf(fmaxf(rintf(w[(size_t)o * K_DIM + k] / sw) + zw, -128.f), 127.f) - zw;
        acc += (qx * sx) * (qw * sw);
    }
    out[idx] = acc + bias[o];
}

// ---------------------------------------------------------------------------
extern "C" void kernel_launch(void* const* d_in, const int* in_sizes, int n_in,
                              void* d_out, int out_size, void* d_ws, size_t ws_size,
                              hipStream_t stream)
{
    const float* x    = (const float*)d_in[0];
    const float* w    = (const float*)d_in[1];
    const float* bias = (const float*)d_in[2];
    const float* asc  = (const float*)d_in[3];
    const float* wsc  = (const float*)d_in[4];
    const int*   azp  = (const int*)d_in[5];
    const int*   wzp  = (const int*)d_in[6];
    float* out = (float*)d_out;

    size_t xq_bytes = (size_t)M_DIM * K_DIM;   // 64 MiB
    size_t wq_bytes = (size_t)N_DIM * K_DIM;   // 16 MiB

    if (ws_size < xq_bytes + wq_bytes) {
        int total = M_DIM * N_DIM;
        fallback_kernel<<<(total + 255) / 256, 256, 0, stream>>>(
            x, w, bias, asc, wsc, azp, wzp, out);
        return;
    }

    signed char* xq = (signed char*)d_ws;
    signed char* wq = (signed char*)d_ws + xq_bytes;

    quant_x_kernel<<<(M_DIM * (K_DIM / 16)) / 256, 256, 0, stream>>>(x, asc, azp, xq);
    quant_w_kernel<<<(N_DIM * (K_DIM / 16)) / 256, 256, 0, stream>>>(w, wsc, wzp, wq);
    gemm_i8_256<<<(M_DIM / 256) * (N_DIM / 256), 512, 0, stream>>>(
        xq, wq, bias, asc, wsc, out);
}